// Round 19
// baseline (342.210 us; speedup 1.0000x reference)
//
#include <hip/hip_runtime.h>
#include <hip/hip_bf16.h>
#include <math.h>

#define NODES 50000
#define EDGES 10000
#define NNZ   800000
#define FIN   128
#define NHID  128
#define FOUT  64

#define NPART  8                   // key partitions == XCDs (blockIdx%8 binding in fill)
#define NSLICE 128                 // entry slices (read once each)
#define SLICE  (NNZ / NSLICE)      // 6250
#define CAP    1024                // staging bucket capacity (mean 781, +9 sigma)
#define EP     (EDGES / NPART)     // 1250 edge keys / partition
#define EWORDS (EDGES / 2)         // 5000 packed hist words (full edge range)
#define VP     (NODES / NPART)     // 6250 vertex keys / partition
#define VPW    (VP / 2)            // 3125 packed words
#define VSUB   16                  // vertex sub-blocks per partition
#define SLPER  (NSLICE / VSUB)     // 8 slices per sub-block

#define EFILL  (NPART * NSLICE)    // 1024 edge-fill blocks
#define VFILL  (NPART * VSUB)      // 128 vertex-fill blocks
#define WCONV_BLOCKS 128
#define GEMM_BLOCKS  ((NODES + 63) / 64)  // 782
#define PERMF_BLOCKS 64
#define NHIST  13                  // degree-hist blocks appended to scan2
#define EDGE_BLOCKS  (EDGES * 64 / 256)   // 2500
#define NF_BLOCKS    (NODES / 16)         // 3125

#define XL_STRIDE 144              // LDS row stride in ushorts

typedef __attribute__((ext_vector_type(8))) short bf16x8;
typedef __attribute__((ext_vector_type(4))) float f32x4;
typedef unsigned short ushort_t;
typedef unsigned int uint_t;

__device__ __forceinline__ ushort_t f2b(float f) {
    __hip_bfloat16 h = __float2bfloat16(f);
    return *reinterpret_cast<ushort_t*>(&h);
}
__device__ __forceinline__ float u2f(unsigned u) {
    union { unsigned u; float f; } c; c.u = u; return c.f;
}
__device__ __forceinline__ float us2f(ushort_t u) { return u2f((unsigned)u << 16); }
__device__ __forceinline__ unsigned pk2(float lo, float hi) {
    return (unsigned)f2b(lo) | ((unsigned)f2b(hi) << 16);
}
#define ACC8(d)                                             \
    do {                                                    \
        a[0] += u2f((d).x << 16); a[1] += u2f((d).x & 0xffff0000u); \
        a[2] += u2f((d).y << 16); a[3] += u2f((d).y & 0xffff0000u); \
        a[4] += u2f((d).z << 16); a[5] += u2f((d).z & 0xffff0000u); \
        a[6] += u2f((d).w << 16); a[7] += u2f((d).w & 0xffff0000u); \
    } while (0)

// ---- K1: one pass over entries: edge hist (LDS) + radix-stage both sides | wconv ----
__global__ __launch_bounds__(256)
void hist_stage_wconv_kernel(const int* __restrict__ vertex, const int* __restrict__ edges,
                             uint_t* __restrict__ cbe,
                             uint_t* __restrict__ stage_e, uint_t* __restrict__ stage_v,
                             int* __restrict__ cnt_se, int* __restrict__ cnt_sv,
                             const float* __restrict__ W0, const float* __restrict__ Ws,
                             const float* __restrict__ Wout,
                             ushort_t* __restrict__ Wt0, ushort_t* __restrict__ WsT,
                             ushort_t* __restrict__ WoutT) {
    __shared__ uint_t eh[EWORDS];       // 20 KB packed edge hist
    __shared__ uint_t cse[NPART], csv[NPART];
    const int t = threadIdx.x;
    if (blockIdx.x < NSLICE) {
        const int b = blockIdx.x;
        for (int w = t; w < EWORDS; w += 256) eh[w] = 0;
        if (t < NPART) { cse[t] = 0; csv[t] = 0; }
        __syncthreads();
        const int base = b * SLICE;
        for (int i = base + t; i < base + SLICE; i += 256) {
            const int e = edges[i], v = vertex[i];
            atomicAdd(&eh[e >> 1], 1u << ((e & 1) * 16));
            const int pe = e / EP;
            const uint_t pose = atomicAdd(&cse[pe], 1u);
            stage_e[(size_t)(pe * NSLICE + b) * CAP + pose] = ((uint_t)e << 16) | (uint_t)v;
            const int pv = v / VP;
            const uint_t posv = atomicAdd(&csv[pv], 1u);
            stage_v[(size_t)(pv * NSLICE + b) * CAP + posv] = ((uint_t)v << 16) | (uint_t)e;
        }
        __syncthreads();
        for (int w = t; w < EWORDS; w += 256) cbe[b * EWORDS + w] = eh[w];
        if (t < NPART) {
            cnt_se[t * NSLICE + b] = (int)cse[t];
            cnt_sv[t * NSLICE + b] = (int)csv[t];
        }
    } else {                                     // ---- weight transpose/convert ----
        const int i = (blockIdx.x - NSLICE) * 256 + t;
        if (i < 128 * 128) { int c = i >> 7, k = i & 127; Wt0[c * 128 + k] = f2b(W0[k * 128 + c]); }
        if (i < 2 * 128 * 128) {
            int l = i >> 14, r = i & 16383, c = r >> 7, k = r & 127;
            WsT[l * 16384 + c * 128 + k] = f2b(Ws[l * 16384 + k * 128 + c]);
        }
        if (i < 64 * 128) { int c = i >> 7, k = i & 127; WoutT[c * 128 + k] = f2b(Wout[k * 64 + c]); }
    }
}

// ---- K1.5: per-partition vertex hist from staged data | colscan of edge counts ----
__global__ __launch_bounds__(256)
void vhist_colscane_kernel(const uint_t* __restrict__ stage_v, const int* __restrict__ cnt_sv,
                           uint_t* __restrict__ cbv,
                           uint_t* __restrict__ cbe, int* __restrict__ cnt_e) {
    const int t = threadIdx.x;
    if (blockIdx.x < VFILL) {                    // 128 vertex-hist blocks
        __shared__ uint_t vh[VPW];               // 12.5 KB
        const int p = blockIdx.x & 7, s = blockIdx.x >> 3;
        for (int w = t; w < VPW; w += 256) vh[w] = 0;
        __syncthreads();
        for (int sl = s * SLPER; sl < (s + 1) * SLPER; ++sl) {
            const int n = cnt_sv[p * NSLICE + sl];
            const uint_t* sv = stage_v + (size_t)(p * NSLICE + sl) * CAP;
            for (int j = t; j < n; j += 256) {
                const int vk = (int)(sv[j] >> 16) - p * VP;
                atomicAdd(&vh[vk >> 1], 1u << ((vk & 1) * 16));
            }
        }
        __syncthreads();
        for (int w = t; w < VPW; w += 256)
            cbv[(size_t)(p * VSUB + s) * VPW + w] = vh[w];
    } else {                                     // colscan over edge slice-counts
        const int flat = (blockIdx.x - VFILL) * 256 + t;
        if (flat < EWORDS) {
            uint_t s0 = 0, s1 = 0;
            for (int b = 0; b < NSLICE; ++b) {
                uint_t* q = &cbe[b * EWORDS + flat];
                const uint_t u = *q; *q = s0 | (s1 << 16);
                s0 += u & 0xffffu; s1 += u >> 16;
            }
            cnt_e[2 * flat]     = (int)s0;
            cnt_e[2 * flat + 1] = (int)s1;
        }
    }
}

// ---- K2a: colscan of vertex sub-block counts ----
__global__ __launch_bounds__(256)
void colscanv_kernel(uint_t* __restrict__ cbv, int* __restrict__ cnt_v) {
    const int flat = blockIdx.x * 256 + (int)threadIdx.x;
    if (flat < NPART * VPW) {
        const int p = flat / VPW, w = flat % VPW;
        uint_t s0 = 0, s1 = 0;
        for (int s = 0; s < VSUB; ++s) {
            uint_t* q = &cbv[(size_t)(p * VSUB + s) * VPW + w];
            const uint_t u = *q; *q = s0 | (s1 << 16);
            s0 += u & 0xffffu; s1 += u >> 16;
        }
        cnt_v[p * VP + 2 * w]     = (int)s0;
        cnt_v[p * VP + 2 * w + 1] = (int)s1;
    }
}

// ---- exclusive scan, 8 items/thread, single 1024-thread block ----
__device__ __forceinline__ void scan_impl(const int* __restrict__ cnt, int* __restrict__ rp,
                                          const int n) {
    __shared__ int wsum[16];
    __shared__ int carry_sh;
    const int t = threadIdx.x, lane = t & 63, w = t >> 6;
    if (t == 0) carry_sh = 0;
    __syncthreads();
    for (int base = 0; base < n; base += 8192) {
        const int idx = base + t * 8;
        int v[8];
        if (idx + 8 <= n) {
            const int4 a = *(const int4*)(cnt + idx);
            const int4 b = *(const int4*)(cnt + idx + 4);
            v[0] = a.x; v[1] = a.y; v[2] = a.z; v[3] = a.w;
            v[4] = b.x; v[5] = b.y; v[6] = b.z; v[7] = b.w;
        } else {
#pragma unroll
            for (int j = 0; j < 8; ++j) v[j] = (idx + j < n) ? cnt[idx + j] : 0;
        }
        int sum8 = 0;
#pragma unroll
        for (int j = 0; j < 8; ++j) sum8 += v[j];
        int x = sum8;
#pragma unroll
        for (int o = 1; o < 64; o <<= 1) {
            int y = __shfl_up(x, o);
            if (lane >= o) x += y;
        }
        if (lane == 63) wsum[w] = x;
        __syncthreads();
        if (t < 16) {
            int s = wsum[t];
#pragma unroll
            for (int o = 1; o < 16; o <<= 1) {
                int y = __shfl_up(s, o);
                if (t >= o) s += y;
            }
            wsum[t] = s;
        }
        __syncthreads();
        const int carry = carry_sh;
        int pre = carry + (x - sum8) + (w ? wsum[w - 1] : 0);
        if (idx < n) {
#pragma unroll
            for (int j = 0; j < 8; ++j)
                if (idx + j < n) { rp[idx + j] = pre; pre += v[j]; }
        }
        __syncthreads();
        if (t == 1023) carry_sh = carry + wsum[15];
        __syncthreads();
    }
    if (t == 0) rp[n] = carry_sh;
}

// ---- K2b: both rp scans | degree histogram (256 bins) ----
__global__ __launch_bounds__(1024)
void scan2_hist_kernel(const int* __restrict__ cnt_e, int* __restrict__ rp_e,
                       const int* __restrict__ cnt_v, int* __restrict__ rp_v,
                       int* __restrict__ dhist) {
    if (blockIdx.x == 0) { scan_impl(cnt_e, rp_e, EDGES); return; }
    if (blockIdx.x == 1) { scan_impl(cnt_v, rp_v, NODES); return; }
    __shared__ int h[256];
    const int t = threadIdx.x;
    if (t < 256) h[t] = 0;
    __syncthreads();
    for (int v = (blockIdx.x - 2) * 1024 + t; v < NODES; v += NHIST * 1024)
        atomicAdd(&h[min(cnt_v[v], 255)], 1);
    __syncthreads();
    if (t < 256 && h[t]) atomicAdd(&dhist[t], h[t]);
}

// ---- K2c: exclusive scan of 256 degree bins -> bucket cursors ----
__global__ __launch_bounds__(256)
void binscan_kernel(const int* __restrict__ dhist, int* __restrict__ bcur) {
    __shared__ int wsum[4];
    const int t = threadIdx.x, lane = t & 63, w = t >> 6;
    const int v = dhist[t];
    int x = v;
#pragma unroll
    for (int o = 1; o < 64; o <<= 1) {
        int y = __shfl_up(x, o);
        if (lane >= o) x += y;
    }
    if (lane == 63) wsum[w] = x;
    __syncthreads();
    if (t == 0) {
        int s = 0;
        for (int i = 0; i < 4; ++i) { const int tv = wsum[i]; wsum[i] = s; s += tv; }
    }
    __syncthreads();
    bcur[t] = x - v + wsum[w];
}

// ---- K3: fill both CSRs from staged data | input GEMM | vperm counting-sort fill ----
__global__ __launch_bounds__(256)
void fill_gemm_kernel(const uint_t* __restrict__ stage_e, const uint_t* __restrict__ stage_v,
                      const int* __restrict__ cnt_se, const int* __restrict__ cnt_sv,
                      const uint_t* __restrict__ cbe, const uint_t* __restrict__ cbv,
                      const int* __restrict__ rp_e, const int* __restrict__ rp_v,
                      ushort_t* __restrict__ col_e, ushort_t* __restrict__ col_v,
                      const float* __restrict__ X, const ushort_t* __restrict__ Wt,
                      const float* __restrict__ bias, ushort_t* __restrict__ x0,
                      const int* __restrict__ cnt_vd, int* __restrict__ bcur,
                      int* __restrict__ vperm) {
    __shared__ uint_t cur[VP];   // 25 KB (e-fill uses first EP)
    const int t = threadIdx.x;
    if (blockIdx.x < EFILL) {                    // ---- edge fill (p = blockIdx%8 -> XCD) ----
        const int p = blockIdx.x & 7, sl = blockIdx.x >> 3;
        for (int k = t; k < EP; k += 256) {
            const int key = p * EP + k;
            const uint_t word = cbe[sl * EWORDS + (key >> 1)];
            const uint_t b16 = (k & 1) ? (word >> 16) : (word & 0xffffu);
            cur[k] = (uint_t)rp_e[key] + b16;
        }
        __syncthreads();
        const int n = cnt_se[p * NSLICE + sl];
        const uint_t* se = stage_e + (size_t)(p * NSLICE + sl) * CAP;
        for (int j = t; j < n; j += 256) {
            const uint_t u = se[j];
            const uint_t pos = atomicAdd(&cur[(int)(u >> 16) - p * EP], 1u);
            col_e[pos] = (ushort_t)(u & 0xffffu);
        }
        return;
    }
    if (blockIdx.x < EFILL + VFILL) {            // ---- vertex fill ----
        const int vb = blockIdx.x - EFILL;       // EFILL%8==0 keeps %8 binding
        const int p = vb & 7, s = vb >> 3;
        for (int k = t; k < VP; k += 256) {
            const int key = p * VP + k;
            const uint_t word = cbv[(size_t)(p * VSUB + s) * VPW + (k >> 1)];
            const uint_t b16 = (k & 1) ? (word >> 16) : (word & 0xffffu);
            cur[k] = (uint_t)rp_v[key] + b16;
        }
        __syncthreads();
        for (int sl = s * SLPER; sl < (s + 1) * SLPER; ++sl) {
            const int n = cnt_sv[p * NSLICE + sl];
            const uint_t* sv = stage_v + (size_t)(p * NSLICE + sl) * CAP;
            for (int j = t; j < n; j += 256) {
                const uint_t u = sv[j];
                const uint_t pos = atomicAdd(&cur[(int)(u >> 16) - p * VP], 1u);
                col_v[pos] = (ushort_t)(u & 0xffffu);
            }
        }
        return;
    }
    if (blockIdx.x >= EFILL + VFILL + GEMM_BLOCKS) {   // ---- vperm fill ----
        const int pb = blockIdx.x - (EFILL + VFILL + GEMM_BLOCKS);
        for (int v = pb * 256 + t; v < NODES; v += PERMF_BLOCKS * 256) {
            const int bin = min(cnt_vd[v], 255);
            const int pos = atomicAdd(&bcur[bin], 1);
            vperm[pos] = v;
        }
        return;
    }
    // ---- input GEMM: x0 = relu(Xin @ W0 + b0) ----
    const int lane = threadIdx.x & 63, wave = threadIdx.x >> 6;
    const int row0 = (blockIdx.x - (EFILL + VFILL)) * 64 + wave * 16;
    if (row0 >= NODES) return;
    const int r = lane & 15, kb = lane >> 4;
    const int row = row0 + r;
    bf16x8 a[4];
#pragma unroll
    for (int k0 = 0; k0 < 4; ++k0) {
        const float* p = X + (size_t)row * FIN + k0 * 32 + kb * 8;
        const float4 lo = *(const float4*)p;
        const float4 hi = *(const float4*)(p + 4);
        bf16x8 tt;
        tt[0] = f2b(lo.x); tt[1] = f2b(lo.y); tt[2] = f2b(lo.z); tt[3] = f2b(lo.w);
        tt[4] = f2b(hi.x); tt[5] = f2b(hi.y); tt[6] = f2b(hi.z); tt[7] = f2b(hi.w);
        a[k0] = tt;
    }
    f32x4 acc[8];
#pragma unroll
    for (int c0 = 0; c0 < 8; ++c0) {
        const float bv = bias[c0 * 16 + r];
        acc[c0] = (f32x4){bv, bv, bv, bv};
    }
#pragma unroll
    for (int k0 = 0; k0 < 4; ++k0)
#pragma unroll
        for (int c0 = 0; c0 < 8; ++c0) {
            const bf16x8 b = *(const bf16x8*)(Wt + (size_t)(c0 * 16 + r) * FIN + k0 * 32 + kb * 8);
            acc[c0] = __builtin_amdgcn_mfma_f32_16x16x32_bf16(a[k0], b, acc[c0], 0, 0, 0);
        }
#pragma unroll
    for (int c0 = 0; c0 < 8; ++c0) {
        const int col = c0 * 16 + r;
#pragma unroll
        for (int v = 0; v < 4; ++v) {
            const int orow = row0 + kb * 4 + v;
            float val = acc[c0][v];
            val = val > 0.f ? val : 0.f;
            x0[(size_t)orow * NHID + col] = f2b(val);
        }
    }
}

// ---- edge gather: 16 lanes/row, 4-deep load batches, 4 rows in flight per wave ----
__global__ __launch_bounds__(256)
void edge_gather_kernel(const ushort_t* __restrict__ x, const int* __restrict__ rp,
                        const ushort_t* __restrict__ ci, ushort_t* __restrict__ Xe,
                        float* __restrict__ out_xe) {
    const int e = (blockIdx.x * 256 + (int)threadIdx.x) >> 6;
    if (e >= EDGES) return;
    const int lane = threadIdx.x & 63;
    const int sub = lane >> 4, lr = lane & 15;
    const int beg = rp[e], end = rp[e + 1];
    float a[8] = {};
    for (int base = beg; base < end; base += 64) {
        const int m = min(64, end - base);
        const int idx_l = (lane < m) ? (int)ci[base + lane] : 0;
#pragma unroll
        for (int jb = 0; jb < 4; ++jb) {         // 4 batches of 4 in-flight loads
            uint4 d[4];
#pragma unroll
            for (int j = 0; j < 4; ++j) {
                const int slot = (jb * 4 + j) * 4 + sub;
                const int src = __shfl(idx_l, slot & 63);
                if (slot < m) d[j] = *(const uint4*)(x + (size_t)src * NHID + lr * 8);
            }
#pragma unroll
            for (int j = 0; j < 4; ++j)
                if ((jb * 4 + j) * 4 + sub < m) ACC8(d[j]);
        }
    }
#pragma unroll
    for (int k = 0; k < 8; ++k) {
        a[k] += __shfl_xor(a[k], 16);
        a[k] += __shfl_xor(a[k], 32);
    }
    const float inv = 1.f / (float)max(end - beg, 1);
    if (sub == 0) {
        float vv[8];
#pragma unroll
        for (int k = 0; k < 8; ++k) vv[k] = a[k] * inv;
        uint4 o;
        o.x = pk2(vv[0], vv[1]); o.y = pk2(vv[2], vv[3]);
        o.z = pk2(vv[4], vv[5]); o.w = pk2(vv[6], vv[7]);
        *(uint4*)(Xe + (size_t)e * NHID + lr * 8) = o;
        if (out_xe) {
            const float4 f0 = {vv[0], vv[1], vv[2], vv[3]};
            const float4 f1 = {vv[4], vv[5], vv[6], vv[7]};
            *(float4*)(out_xe + (size_t)e * NHID + lr * 8) = f0;
            *(float4*)(out_xe + (size_t)e * NHID + lr * 8 + 4) = f1;
        }
    }
}

// ---- node phase 1 (degree-sorted): gather + mean + L2-norm + residual -> LDS ----
__device__ __forceinline__ void node_phase1(const ushort_t* __restrict__ Xe,
                                            const int* __restrict__ rp,
                                            const ushort_t* __restrict__ ci,
                                            const ushort_t* __restrict__ x0,
                                            const int* __restrict__ vperm,
                                            const int vbase,
                                            ushort_t* __restrict__ xl,
                                            int* __restrict__ vmap) {
    const int lane = threadIdx.x & 63, wave = threadIdx.x >> 6;
    const int sub = lane >> 4, lr = lane & 15;
    const int row = wave * 4 + sub;
    const int v = vperm[vbase + row];
    if (lr == 0) vmap[row] = v;
    const int beg = rp[v], end = rp[v + 1];
    const int sbase = lane & 48;
    // prefetch x0 row (independent of gather)
    const uint4 u0 = *(const uint4*)(x0 + (size_t)v * NHID + lr * 8);
    float a[8] = {};
    for (int base = beg; base < end; base += 16) {
        const int m = min(16, end - base);
        const int idx_l = (lr < m) ? (int)ci[base + lr] : 0;
#pragma unroll
        for (int jb = 0; jb < 4; ++jb) {         // 4 batches of 4 in-flight loads
            uint4 d[4];
#pragma unroll
            for (int j = 0; j < 4; ++j) {
                const int slot = jb * 4 + j;
                const int src = __shfl(idx_l, sbase + slot);
                if (slot < m) d[j] = *(const uint4*)(Xe + (size_t)src * NHID + lr * 8);
            }
#pragma unroll
            for (int j = 0; j < 4; ++j)
                if (jb * 4 + j < m) ACC8(d[j]);
        }
    }
    const float inv = 1.f / (float)max(end - beg, 1);
    float mk[8], s = 0.f;
#pragma unroll
    for (int k = 0; k < 8; ++k) { mk[k] = a[k] * inv; s += mk[k] * mk[k]; }
    s += __shfl_xor(s, 1); s += __shfl_xor(s, 2);
    s += __shfl_xor(s, 4); s += __shfl_xor(s, 8);
    const float norm = sqrtf(s);
    const float scale = norm > 0.f ? 1.f / fmaxf(norm, 1e-30f) : 0.f;
    float xv[8];
    xv[0] = u2f(u0.x << 16); xv[1] = u2f(u0.x & 0xffff0000u);
    xv[2] = u2f(u0.y << 16); xv[3] = u2f(u0.y & 0xffff0000u);
    xv[4] = u2f(u0.z << 16); xv[5] = u2f(u0.z & 0xffff0000u);
    xv[6] = u2f(u0.w << 16); xv[7] = u2f(u0.w & 0xffff0000u);
    float o[8];
#pragma unroll
    for (int k = 0; k < 8; ++k) o[k] = 0.9f * mk[k] * scale + 0.1f * xv[k];
    uint4 ou;
    ou.x = pk2(o[0], o[1]); ou.y = pk2(o[2], o[3]);
    ou.z = pk2(o[4], o[5]); ou.w = pk2(o[6], o[7]);
    *(uint4*)(xl + row * XL_STRIDE + lr * 8) = ou;
}

// ---- K6: node gather+post fused with layer-1 GEMM ----
__global__ __launch_bounds__(256)
void node_l1_kernel(const ushort_t* __restrict__ Xe, const int* __restrict__ rp,
                    const ushort_t* __restrict__ ci, const ushort_t* __restrict__ x0,
                    const int* __restrict__ vperm,
                    const ushort_t* __restrict__ Wt, float beta,
                    ushort_t* __restrict__ xout) {
    __shared__ ushort_t xl[16 * XL_STRIDE];
    __shared__ int vmap[16];
    const int vbase = blockIdx.x * 16;
    node_phase1(Xe, rp, ci, x0, vperm, vbase, xl, vmap);
    __syncthreads();
    const int lane = threadIdx.x & 63, wave = threadIdx.x >> 6;
    const int r = lane & 15, kb = lane >> 4;
    bf16x8 a2[4];
#pragma unroll
    for (int k0 = 0; k0 < 4; ++k0)
        a2[k0] = *(const bf16x8*)(xl + r * XL_STRIDE + k0 * 32 + kb * 8);
    f32x4 acc[2] = {};
#pragma unroll
    for (int k0 = 0; k0 < 4; ++k0)
#pragma unroll
        for (int cc = 0; cc < 2; ++cc) {
            const int c0 = wave * 2 + cc;
            const bf16x8 b = *(const bf16x8*)(Wt + (size_t)(c0 * 16 + r) * NHID + k0 * 32 + kb * 8);
            acc[cc] = __builtin_amdgcn_mfma_f32_16x16x32_bf16(a2[k0], b, acc[cc], 0, 0, 0);
        }
    const float xim = 1.f - beta;
#pragma unroll
    for (int cc = 0; cc < 2; ++cc) {
        const int col = (wave * 2 + cc) * 16 + r;
#pragma unroll
        for (int v = 0; v < 4; ++v) {
            const int row = kb * 4 + v;
            const float xi = us2f(xl[row * XL_STRIDE + col]);
            float val = xim * xi + beta * acc[cc][v];
            val = val > 0.f ? val : 0.f;
            xout[(size_t)vmap[row] * NHID + col] = f2b(val);
        }
    }
}

// ---- K8: node gather+post fused with layer-2 GEMM AND output GEMM ----
__global__ __launch_bounds__(256)
void node_l2_out_kernel(const ushort_t* __restrict__ Xe, const int* __restrict__ rp,
                        const ushort_t* __restrict__ ci, const ushort_t* __restrict__ x0,
                        const int* __restrict__ vperm,
                        const ushort_t* __restrict__ Wt, const ushort_t* __restrict__ WoT,
                        const float* __restrict__ bias, float beta,
                        float* __restrict__ out) {
    __shared__ ushort_t xl[16 * XL_STRIDE];
    __shared__ ushort_t x2[16 * XL_STRIDE];
    __shared__ int vmap[16];
    const int vbase = blockIdx.x * 16;
    node_phase1(Xe, rp, ci, x0, vperm, vbase, xl, vmap);
    __syncthreads();
    const int lane = threadIdx.x & 63, wave = threadIdx.x >> 6;
    const int r = lane & 15, kb = lane >> 4;
    {
        bf16x8 a2[4];
#pragma unroll
        for (int k0 = 0; k0 < 4; ++k0)
            a2[k0] = *(const bf16x8*)(xl + r * XL_STRIDE + k0 * 32 + kb * 8);
        f32x4 acc[2] = {};
#pragma unroll
        for (int k0 = 0; k0 < 4; ++k0)
#pragma unroll
            for (int cc = 0; cc < 2; ++cc) {
                const int c0 = wave * 2 + cc;
                const bf16x8 b = *(const bf16x8*)(Wt + (size_t)(c0 * 16 + r) * NHID + k0 * 32 + kb * 8);
                acc[cc] = __builtin_amdgcn_mfma_f32_16x16x32_bf16(a2[k0], b, acc[cc], 0, 0, 0);
            }
        const float xim = 1.f - beta;
#pragma unroll
        for (int cc = 0; cc < 2; ++cc) {
            const int col = (wave * 2 + cc) * 16 + r;
#pragma unroll
            for (int v = 0; v < 4; ++v) {
                const int row = kb * 4 + v;
                const float xi = us2f(xl[row * XL_STRIDE + col]);
                float val = xim * xi + beta * acc[cc][v];
                val = val > 0.f ? val : 0.f;
                x2[row * XL_STRIDE + col] = f2b(val);
            }
        }
    }
    __syncthreads();
    bf16x8 a3[4];
#pragma unroll
    for (int k0 = 0; k0 < 4; ++k0)
        a3[k0] = *(const bf16x8*)(x2 + r * XL_STRIDE + k0 * 32 + kb * 8);
    const float bv = bias[wave * 16 + r];
    f32x4 facc = (f32x4){bv, bv, bv, bv};
#pragma unroll
    for (int k0 = 0; k0 < 4; ++k0) {
        const bf16x8 b = *(const bf16x8*)(WoT + (size_t)(wave * 16 + r) * NHID + k0 * 32 + kb * 8);
        facc = __builtin_amdgcn_mfma_f32_16x16x32_bf16(a3[k0], b, facc, 0, 0, 0);
    }
#pragma unroll
    for (int v = 0; v < 4; ++v) {
        const int row = kb * 4 + v;
        out[(size_t)vmap[row] * FOUT + wave * 16 + r] = facc[v];
    }
}

extern "C" void kernel_launch(void* const* d_in, const int* in_sizes, int n_in,
                              void* d_out, int out_size, void* d_ws, size_t ws_size,
                              hipStream_t stream) {
    const float* x_in  = (const float*)d_in[0];
    const float* W0    = (const float*)d_in[1];
    const float* b0    = (const float*)d_in[2];
    const float* Ws    = (const float*)d_in[3];
    const float* Wout  = (const float*)d_in[4];
    const float* bout  = (const float*)d_in[5];
    const int* vertex  = (const int*)d_in[6];
    const int* edges   = (const int*)d_in[7];

    ushort_t* Xe   = (ushort_t*)d_ws;                       // EDGES*NHID bf16
    ushort_t* x    = Xe + (size_t)EDGES * NHID;             // NODES*NHID bf16
    ushort_t* x0   = x  + (size_t)NODES * NHID;             // NODES*NHID bf16
    ushort_t* Wt0  = x0 + (size_t)NODES * NHID;             // 128*128
    ushort_t* WsT  = Wt0 + 128 * 128;                       // 2*128*128
    ushort_t* WoutT= WsT + 2 * 128 * 128;                   // 64*128
    int* cnt_e = (int*)(WoutT + 64 * 128);                  // EDGES
    int* cnt_v = cnt_e + EDGES;                             // NODES
    int* rp_e  = cnt_v + NODES;                             // EDGES+1 (pad to 10004)
    int* rp_v  = rp_e + EDGES + 4;                          // NODES+1 (pad to 50004)
    int* cnt_se = rp_v + NODES + 4;                         // NPART*NSLICE = 1024
    int* cnt_sv = cnt_se + NPART * NSLICE;                  // 1024
    int* dhist  = cnt_sv + NPART * NSLICE;                  // 256
    int* bcur   = dhist + 256;                              // 256
    int* vperm  = bcur + 256;                               // NODES
    uint_t* cbe = (uint_t*)(vperm + NODES);                 // NSLICE*EWORDS = 640K words
    uint_t* cbv = cbe + (size_t)NSLICE * EWORDS;            // NPART*VSUB*VPW = 400K words
    uint_t* stage_e = cbv + (size_t)NPART * VSUB * VPW;     // 4 MB
    uint_t* stage_v = stage_e + (size_t)NPART * NSLICE * CAP; // 4 MB
    ushort_t* col_e = (ushort_t*)(stage_v + (size_t)NPART * NSLICE * CAP);  // NNZ u16
    ushort_t* col_v = col_e + NNZ;                          // NNZ u16

    float* out    = (float*)d_out;                          // [NODES, FOUT]
    float* out_xe = out + (size_t)NODES * FOUT;             // [EDGES, NHID]

    hipMemsetAsync(dhist, 0, 256 * sizeof(int), stream);

    // K1: one pass over entries (edge hist + radix staging) + weight conversion
    hist_stage_wconv_kernel<<<NSLICE + WCONV_BLOCKS, 256, 0, stream>>>(
        vertex, edges, cbe, stage_e, stage_v, cnt_se, cnt_sv,
        W0, Ws, Wout, Wt0, WsT, WoutT);
    // K1.5: vertex hist (per partition, from staged) + edge colscan
    vhist_colscane_kernel<<<VFILL + (EWORDS + 255) / 256, 256, 0, stream>>>(
        stage_v, cnt_sv, cbv, cbe, cnt_e);
    // K2a: vertex colscan
    colscanv_kernel<<<(NPART * VPW + 255) / 256, 256, 0, stream>>>(cbv, cnt_v);
    // K2b: rp scans + degree histogram
    scan2_hist_kernel<<<2 + NHIST, 1024, 0, stream>>>(cnt_e, rp_e, cnt_v, rp_v, dhist);
    // K2c: bin scan -> bucket cursors
    binscan_kernel<<<1, 256, 0, stream>>>(dhist, bcur);
    // K3: fill both CSRs + input GEMM + vperm counting-sort fill
    fill_gemm_kernel<<<EFILL + VFILL + GEMM_BLOCKS + PERMF_BLOCKS, 256, 0, stream>>>(
        stage_e, stage_v, cnt_se, cnt_sv, cbe, cbv, rp_e, rp_v,
        col_e, col_v, x_in, Wt0, b0, x0, cnt_v, bcur, vperm);

    const float betas[2] = {logf(1.5f), logf(1.25f)};  // log(0.5/(i+1)+1)

    // layer 1
    edge_gather_kernel<<<EDGE_BLOCKS, 256, 0, stream>>>(x0, rp_e, col_e, Xe, (float*)nullptr);
    node_l1_kernel<<<NF_BLOCKS, 256, 0, stream>>>(Xe, rp_v, col_v, x0, vperm, WsT, betas[0], x);
    // layer 2
    edge_gather_kernel<<<EDGE_BLOCKS, 256, 0, stream>>>(x, rp_e, col_e, Xe, out_xe);
    node_l2_out_kernel<<<NF_BLOCKS, 256, 0, stream>>>(
        Xe, rp_v, col_v, x0, vperm, WsT + (size_t)NHID * NHID, WoutT, bout, betas[1], out);
}

// Round 20
// 206.117 us; speedup vs baseline: 1.6603x; 1.6603x over previous
//
#include <hip/hip_runtime.h>
#include <hip/hip_bf16.h>
#include <math.h>

#define NODES 50000
#define EDGES 10000
#define NNZ   800000
#define FIN   128
#define NHID  128
#define FOUT  64

#define NPART  8                   // key partitions == XCDs (blockIdx%8 binding in fill)
#define NSLICE 128                 // entry slices (read once each)
#define SLICE  (NNZ / NSLICE)      // 6250
#define CAP    1024                // staging bucket capacity (mean 781, +9 sigma)
#define EP     (EDGES / NPART)     // 1250 edge keys / partition
#define EWORDS (EDGES / 2)         // 5000 packed hist words (full edge range)
#define VP     (NODES / NPART)     // 6250 vertex keys / partition
#define VPW    (VP / 2)            // 3125 packed words
#define VSUB   16                  // vertex sub-blocks per partition
#define SLPER  (NSLICE / VSUB)     // 8 slices per sub-block

#define EFILL  (NPART * NSLICE)    // 1024 edge-fill blocks
#define VFILL  (NPART * VSUB)      // 128 vertex-fill blocks
#define WCONV_BLOCKS 128
#define GEMM_BLOCKS  ((NODES + 63) / 64)  // 782
#define PERMF_BLOCKS 64
#define PCHUNK ((NODES + PERMF_BLOCKS - 1) / PERMF_BLOCKS)  // 782
#define NHIST  13                  // degree-hist blocks appended to scan2
#define EDGE_BLOCKS  (EDGES * 64 / 256)   // 2500
#define NF_BLOCKS    (NODES / 16)         // 3125

#define XL_STRIDE 144              // LDS row stride in ushorts

typedef __attribute__((ext_vector_type(8))) short bf16x8;
typedef __attribute__((ext_vector_type(4))) float f32x4;
typedef unsigned short ushort_t;
typedef unsigned int uint_t;

__device__ __forceinline__ ushort_t f2b(float f) {
    __hip_bfloat16 h = __float2bfloat16(f);
    return *reinterpret_cast<ushort_t*>(&h);
}
__device__ __forceinline__ float u2f(unsigned u) {
    union { unsigned u; float f; } c; c.u = u; return c.f;
}
__device__ __forceinline__ float us2f(ushort_t u) { return u2f((unsigned)u << 16); }
__device__ __forceinline__ unsigned pk2(float lo, float hi) {
    return (unsigned)f2b(lo) | ((unsigned)f2b(hi) << 16);
}
#define ACC8(d)                                             \
    do {                                                    \
        a[0] += u2f((d).x << 16); a[1] += u2f((d).x & 0xffff0000u); \
        a[2] += u2f((d).y << 16); a[3] += u2f((d).y & 0xffff0000u); \
        a[4] += u2f((d).z << 16); a[5] += u2f((d).z & 0xffff0000u); \
        a[6] += u2f((d).w << 16); a[7] += u2f((d).w & 0xffff0000u); \
    } while (0)

// ---- K1: one pass over entries: edge hist (LDS) + radix-stage both sides | wconv ----
__global__ __launch_bounds__(256)
void hist_stage_wconv_kernel(const int* __restrict__ vertex, const int* __restrict__ edges,
                             uint_t* __restrict__ cbe,
                             uint_t* __restrict__ stage_e, uint_t* __restrict__ stage_v,
                             int* __restrict__ cnt_se, int* __restrict__ cnt_sv,
                             const float* __restrict__ W0, const float* __restrict__ Ws,
                             const float* __restrict__ Wout,
                             ushort_t* __restrict__ Wt0, ushort_t* __restrict__ WsT,
                             ushort_t* __restrict__ WoutT) {
    __shared__ uint_t eh[EWORDS];       // 20 KB packed edge hist
    __shared__ uint_t cse[NPART], csv[NPART];
    const int t = threadIdx.x;
    if (blockIdx.x < NSLICE) {
        const int b = blockIdx.x;
        for (int w = t; w < EWORDS; w += 256) eh[w] = 0;
        if (t < NPART) { cse[t] = 0; csv[t] = 0; }
        __syncthreads();
        const int base = b * SLICE;
        for (int i = base + t; i < base + SLICE; i += 256) {
            const int e = edges[i], v = vertex[i];
            atomicAdd(&eh[e >> 1], 1u << ((e & 1) * 16));
            const int pe = e / EP;
            const uint_t pose = atomicAdd(&cse[pe], 1u);
            stage_e[(size_t)(pe * NSLICE + b) * CAP + pose] = ((uint_t)e << 16) | (uint_t)v;
            const int pv = v / VP;
            const uint_t posv = atomicAdd(&csv[pv], 1u);
            stage_v[(size_t)(pv * NSLICE + b) * CAP + posv] = ((uint_t)v << 16) | (uint_t)e;
        }
        __syncthreads();
        for (int w = t; w < EWORDS; w += 256) cbe[b * EWORDS + w] = eh[w];
        if (t < NPART) {
            cnt_se[t * NSLICE + b] = (int)cse[t];
            cnt_sv[t * NSLICE + b] = (int)csv[t];
        }
    } else {                                     // ---- weight transpose/convert ----
        const int i = (blockIdx.x - NSLICE) * 256 + t;
        if (i < 128 * 128) { int c = i >> 7, k = i & 127; Wt0[c * 128 + k] = f2b(W0[k * 128 + c]); }
        if (i < 2 * 128 * 128) {
            int l = i >> 14, r = i & 16383, c = r >> 7, k = r & 127;
            WsT[l * 16384 + c * 128 + k] = f2b(Ws[l * 16384 + k * 128 + c]);
        }
        if (i < 64 * 128) { int c = i >> 7, k = i & 127; WoutT[c * 128 + k] = f2b(Wout[k * 64 + c]); }
    }
}

// ---- K1.5: per-partition vertex hist from staged data | colscan of edge counts ----
__global__ __launch_bounds__(256)
void vhist_colscane_kernel(const uint_t* __restrict__ stage_v, const int* __restrict__ cnt_sv,
                           uint_t* __restrict__ cbv,
                           uint_t* __restrict__ cbe, int* __restrict__ cnt_e) {
    const int t = threadIdx.x;
    if (blockIdx.x < VFILL) {                    // 128 vertex-hist blocks
        __shared__ uint_t vh[VPW];               // 12.5 KB
        const int p = blockIdx.x & 7, s = blockIdx.x >> 3;
        for (int w = t; w < VPW; w += 256) vh[w] = 0;
        __syncthreads();
        for (int sl = s * SLPER; sl < (s + 1) * SLPER; ++sl) {
            const int n = cnt_sv[p * NSLICE + sl];
            const uint_t* sv = stage_v + (size_t)(p * NSLICE + sl) * CAP;
            for (int j = t; j < n; j += 256) {
                const int vk = (int)(sv[j] >> 16) - p * VP;
                atomicAdd(&vh[vk >> 1], 1u << ((vk & 1) * 16));
            }
        }
        __syncthreads();
        for (int w = t; w < VPW; w += 256)
            cbv[(size_t)(p * VSUB + s) * VPW + w] = vh[w];
    } else {                                     // colscan over edge slice-counts
        const int flat = (blockIdx.x - VFILL) * 256 + t;
        if (flat < EWORDS) {
            uint_t s0 = 0, s1 = 0;
            for (int b = 0; b < NSLICE; ++b) {
                uint_t* q = &cbe[b * EWORDS + flat];
                const uint_t u = *q; *q = s0 | (s1 << 16);
                s0 += u & 0xffffu; s1 += u >> 16;
            }
            cnt_e[2 * flat]     = (int)s0;
            cnt_e[2 * flat + 1] = (int)s1;
        }
    }
}

// ---- K2a: colscan of vertex sub-block counts ----
__global__ __launch_bounds__(256)
void colscanv_kernel(uint_t* __restrict__ cbv, int* __restrict__ cnt_v) {
    const int flat = blockIdx.x * 256 + (int)threadIdx.x;
    if (flat < NPART * VPW) {
        const int p = flat / VPW, w = flat % VPW;
        uint_t s0 = 0, s1 = 0;
        for (int s = 0; s < VSUB; ++s) {
            uint_t* q = &cbv[(size_t)(p * VSUB + s) * VPW + w];
            const uint_t u = *q; *q = s0 | (s1 << 16);
            s0 += u & 0xffffu; s1 += u >> 16;
        }
        cnt_v[p * VP + 2 * w]     = (int)s0;
        cnt_v[p * VP + 2 * w + 1] = (int)s1;
    }
}

// ---- exclusive scan, 8 items/thread, single 1024-thread block ----
__device__ __forceinline__ void scan_impl(const int* __restrict__ cnt, int* __restrict__ rp,
                                          const int n) {
    __shared__ int wsum[16];
    __shared__ int carry_sh;
    const int t = threadIdx.x, lane = t & 63, w = t >> 6;
    if (t == 0) carry_sh = 0;
    __syncthreads();
    for (int base = 0; base < n; base += 8192) {
        const int idx = base + t * 8;
        int v[8];
        if (idx + 8 <= n) {
            const int4 a = *(const int4*)(cnt + idx);
            const int4 b = *(const int4*)(cnt + idx + 4);
            v[0] = a.x; v[1] = a.y; v[2] = a.z; v[3] = a.w;
            v[4] = b.x; v[5] = b.y; v[6] = b.z; v[7] = b.w;
        } else {
#pragma unroll
            for (int j = 0; j < 8; ++j) v[j] = (idx + j < n) ? cnt[idx + j] : 0;
        }
        int sum8 = 0;
#pragma unroll
        for (int j = 0; j < 8; ++j) sum8 += v[j];
        int x = sum8;
#pragma unroll
        for (int o = 1; o < 64; o <<= 1) {
            int y = __shfl_up(x, o);
            if (lane >= o) x += y;
        }
        if (lane == 63) wsum[w] = x;
        __syncthreads();
        if (t < 16) {
            int s = wsum[t];
#pragma unroll
            for (int o = 1; o < 16; o <<= 1) {
                int y = __shfl_up(s, o);
                if (t >= o) s += y;
            }
            wsum[t] = s;
        }
        __syncthreads();
        const int carry = carry_sh;
        int pre = carry + (x - sum8) + (w ? wsum[w - 1] : 0);
        if (idx < n) {
#pragma unroll
            for (int j = 0; j < 8; ++j)
                if (idx + j < n) { rp[idx + j] = pre; pre += v[j]; }
        }
        __syncthreads();
        if (t == 1023) carry_sh = carry + wsum[15];
        __syncthreads();
    }
    if (t == 0) rp[n] = carry_sh;
}

// ---- K2b: both rp scans | degree histogram (256 bins) ----
__global__ __launch_bounds__(1024)
void scan2_hist_kernel(const int* __restrict__ cnt_e, int* __restrict__ rp_e,
                       const int* __restrict__ cnt_v, int* __restrict__ rp_v,
                       int* __restrict__ dhist) {
    if (blockIdx.x == 0) { scan_impl(cnt_e, rp_e, EDGES); return; }
    if (blockIdx.x == 1) { scan_impl(cnt_v, rp_v, NODES); return; }
    __shared__ int h[256];
    const int t = threadIdx.x;
    if (t < 256) h[t] = 0;
    __syncthreads();
    for (int v = (blockIdx.x - 2) * 1024 + t; v < NODES; v += NHIST * 1024)
        atomicAdd(&h[min(cnt_v[v], 255)], 1);
    __syncthreads();
    if (t < 256 && h[t]) atomicAdd(&dhist[t], h[t]);
}

// ---- K2c: exclusive scan of 256 degree bins -> bucket cursors ----
__global__ __launch_bounds__(256)
void binscan_kernel(const int* __restrict__ dhist, int* __restrict__ bcur) {
    __shared__ int wsum[4];
    const int t = threadIdx.x, lane = t & 63, w = t >> 6;
    const int v = dhist[t];
    int x = v;
#pragma unroll
    for (int o = 1; o < 64; o <<= 1) {
        int y = __shfl_up(x, o);
        if (lane >= o) x += y;
    }
    if (lane == 63) wsum[w] = x;
    __syncthreads();
    if (t == 0) {
        int s = 0;
        for (int i = 0; i < 4; ++i) { const int tv = wsum[i]; wsum[i] = s; s += tv; }
    }
    __syncthreads();
    bcur[t] = x - v + wsum[w];
}

// ---- K3: fill both CSRs | input GEMM | vperm fill (block-local hist, no hot atomics) ----
__global__ __launch_bounds__(256)
void fill_gemm_kernel(const uint_t* __restrict__ stage_e, const uint_t* __restrict__ stage_v,
                      const int* __restrict__ cnt_se, const int* __restrict__ cnt_sv,
                      const uint_t* __restrict__ cbe, const uint_t* __restrict__ cbv,
                      const int* __restrict__ rp_e, const int* __restrict__ rp_v,
                      ushort_t* __restrict__ col_e, ushort_t* __restrict__ col_v,
                      const float* __restrict__ X, const ushort_t* __restrict__ Wt,
                      const float* __restrict__ bias, ushort_t* __restrict__ x0,
                      const int* __restrict__ cnt_vd, int* __restrict__ bcur,
                      int* __restrict__ vperm) {
    __shared__ uint_t cur[VP];   // 25 KB (e-fill uses first EP; perm branch aliases 768 ints)
    const int t = threadIdx.x;
    if (blockIdx.x < EFILL) {                    // ---- edge fill (p = blockIdx%8 -> XCD) ----
        const int p = blockIdx.x & 7, sl = blockIdx.x >> 3;
        for (int k = t; k < EP; k += 256) {
            const int key = p * EP + k;
            const uint_t word = cbe[sl * EWORDS + (key >> 1)];
            const uint_t b16 = (k & 1) ? (word >> 16) : (word & 0xffffu);
            cur[k] = (uint_t)rp_e[key] + b16;
        }
        __syncthreads();
        const int n = cnt_se[p * NSLICE + sl];
        const uint_t* se = stage_e + (size_t)(p * NSLICE + sl) * CAP;
        for (int j = t; j < n; j += 256) {
            const uint_t u = se[j];
            const uint_t pos = atomicAdd(&cur[(int)(u >> 16) - p * EP], 1u);
            col_e[pos] = (ushort_t)(u & 0xffffu);
        }
        return;
    }
    if (blockIdx.x < EFILL + VFILL) {            // ---- vertex fill ----
        const int vb = blockIdx.x - EFILL;       // EFILL%8==0 keeps %8 binding
        const int p = vb & 7, s = vb >> 3;
        for (int k = t; k < VP; k += 256) {
            const int key = p * VP + k;
            const uint_t word = cbv[(size_t)(p * VSUB + s) * VPW + (k >> 1)];
            const uint_t b16 = (k & 1) ? (word >> 16) : (word & 0xffffu);
            cur[k] = (uint_t)rp_v[key] + b16;
        }
        __syncthreads();
        for (int sl = s * SLPER; sl < (s + 1) * SLPER; ++sl) {
            const int n = cnt_sv[p * NSLICE + sl];
            const uint_t* sv = stage_v + (size_t)(p * NSLICE + sl) * CAP;
            for (int j = t; j < n; j += 256) {
                const uint_t u = sv[j];
                const uint_t pos = atomicAdd(&cur[(int)(u >> 16) - p * VP], 1u);
                col_v[pos] = (ushort_t)(u & 0xffffu);
            }
        }
        return;
    }
    if (blockIdx.x >= EFILL + VFILL + GEMM_BLOCKS) {   // ---- vperm fill (hierarchical) ----
        const int pb = blockIdx.x - (EFILL + VFILL + GEMM_BLOCKS);
        const int v0 = pb * PCHUNK;
        const int v1 = min(v0 + PCHUNK, NODES);
        int* h   = (int*)cur;          // [256] block-local bin counts
        int* bs  = (int*)cur + 256;    // [256] global base per bin
        int* c2  = (int*)cur + 512;    // [256] block-local cursors
        if (t < 256) { h[t] = 0; c2[t] = 0; }
        __syncthreads();
        for (int v = v0 + t; v < v1; v += 256)
            atomicAdd(&h[min(cnt_vd[v], 255)], 1);
        __syncthreads();
        if (t < 256 && h[t]) bs[t] = atomicAdd(&bcur[t], h[t]);
        __syncthreads();
        for (int v = v0 + t; v < v1; v += 256) {
            const int bin = min(cnt_vd[v], 255);
            const int r = atomicAdd(&c2[bin], 1);
            vperm[bs[bin] + r] = v;
        }
        return;
    }
    // ---- input GEMM: x0 = relu(Xin @ W0 + b0) ----
    const int lane = threadIdx.x & 63, wave = threadIdx.x >> 6;
    const int row0 = (blockIdx.x - (EFILL + VFILL)) * 64 + wave * 16;
    if (row0 >= NODES) return;
    const int r = lane & 15, kb = lane >> 4;
    const int row = row0 + r;
    bf16x8 a[4];
#pragma unroll
    for (int k0 = 0; k0 < 4; ++k0) {
        const float* p = X + (size_t)row * FIN + k0 * 32 + kb * 8;
        const float4 lo = *(const float4*)p;
        const float4 hi = *(const float4*)(p + 4);
        bf16x8 tt;
        tt[0] = f2b(lo.x); tt[1] = f2b(lo.y); tt[2] = f2b(lo.z); tt[3] = f2b(lo.w);
        tt[4] = f2b(hi.x); tt[5] = f2b(hi.y); tt[6] = f2b(hi.z); tt[7] = f2b(hi.w);
        a[k0] = tt;
    }
    f32x4 acc[8];
#pragma unroll
    for (int c0 = 0; c0 < 8; ++c0) {
        const float bv = bias[c0 * 16 + r];
        acc[c0] = (f32x4){bv, bv, bv, bv};
    }
#pragma unroll
    for (int k0 = 0; k0 < 4; ++k0)
#pragma unroll
        for (int c0 = 0; c0 < 8; ++c0) {
            const bf16x8 b = *(const bf16x8*)(Wt + (size_t)(c0 * 16 + r) * FIN + k0 * 32 + kb * 8);
            acc[c0] = __builtin_amdgcn_mfma_f32_16x16x32_bf16(a[k0], b, acc[c0], 0, 0, 0);
        }
#pragma unroll
    for (int c0 = 0; c0 < 8; ++c0) {
        const int col = c0 * 16 + r;
#pragma unroll
        for (int v = 0; v < 4; ++v) {
            const int orow = row0 + kb * 4 + v;
            float val = acc[c0][v];
            val = val > 0.f ? val : 0.f;
            x0[(size_t)orow * NHID + col] = f2b(val);
        }
    }
}

// ---- edge gather: 16 lanes/row, 4-deep load batches, 4 rows in flight per wave ----
__global__ __launch_bounds__(256)
void edge_gather_kernel(const ushort_t* __restrict__ x, const int* __restrict__ rp,
                        const ushort_t* __restrict__ ci, ushort_t* __restrict__ Xe,
                        float* __restrict__ out_xe) {
    const int e = (blockIdx.x * 256 + (int)threadIdx.x) >> 6;
    if (e >= EDGES) return;
    const int lane = threadIdx.x & 63;
    const int sub = lane >> 4, lr = lane & 15;
    const int beg = rp[e], end = rp[e + 1];
    float a[8] = {};
    for (int base = beg; base < end; base += 64) {
        const int m = min(64, end - base);
        const int idx_l = (lane < m) ? (int)ci[base + lane] : 0;
#pragma unroll
        for (int jb = 0; jb < 4; ++jb) {         // 4 batches of 4 in-flight loads
            uint4 d[4];
#pragma unroll
            for (int j = 0; j < 4; ++j) {
                const int slot = (jb * 4 + j) * 4 + sub;
                const int src = __shfl(idx_l, slot & 63);
                if (slot < m) d[j] = *(const uint4*)(x + (size_t)src * NHID + lr * 8);
            }
#pragma unroll
            for (int j = 0; j < 4; ++j)
                if ((jb * 4 + j) * 4 + sub < m) ACC8(d[j]);
        }
    }
#pragma unroll
    for (int k = 0; k < 8; ++k) {
        a[k] += __shfl_xor(a[k], 16);
        a[k] += __shfl_xor(a[k], 32);
    }
    const float inv = 1.f / (float)max(end - beg, 1);
    if (sub == 0) {
        float vv[8];
#pragma unroll
        for (int k = 0; k < 8; ++k) vv[k] = a[k] * inv;
        uint4 o;
        o.x = pk2(vv[0], vv[1]); o.y = pk2(vv[2], vv[3]);
        o.z = pk2(vv[4], vv[5]); o.w = pk2(vv[6], vv[7]);
        *(uint4*)(Xe + (size_t)e * NHID + lr * 8) = o;
        if (out_xe) {
            const float4 f0 = {vv[0], vv[1], vv[2], vv[3]};
            const float4 f1 = {vv[4], vv[5], vv[6], vv[7]};
            *(float4*)(out_xe + (size_t)e * NHID + lr * 8) = f0;
            *(float4*)(out_xe + (size_t)e * NHID + lr * 8 + 4) = f1;
        }
    }
}

// ---- node phase 1 (degree-sorted): gather + mean + L2-norm + residual -> LDS ----
__device__ __forceinline__ void node_phase1(const ushort_t* __restrict__ Xe,
                                            const int* __restrict__ rp,
                                            const ushort_t* __restrict__ ci,
                                            const ushort_t* __restrict__ x0,
                                            const int* __restrict__ vperm,
                                            const int vbase,
                                            ushort_t* __restrict__ xl,
                                            int* __restrict__ vmap) {
    const int lane = threadIdx.x & 63, wave = threadIdx.x >> 6;
    const int sub = lane >> 4, lr = lane & 15;
    const int row = wave * 4 + sub;
    const int v = vperm[vbase + row];
    if (lr == 0) vmap[row] = v;
    const int beg = rp[v], end = rp[v + 1];
    const int sbase = lane & 48;
    // prefetch x0 row (independent of gather)
    const uint4 u0 = *(const uint4*)(x0 + (size_t)v * NHID + lr * 8);
    float a[8] = {};
    for (int base = beg; base < end; base += 16) {
        const int m = min(16, end - base);
        const int idx_l = (lr < m) ? (int)ci[base + lr] : 0;
#pragma unroll
        for (int jb = 0; jb < 4; ++jb) {         // 4 batches of 4 in-flight loads
            uint4 d[4];
#pragma unroll
            for (int j = 0; j < 4; ++j) {
                const int slot = jb * 4 + j;
                const int src = __shfl(idx_l, sbase + slot);
                if (slot < m) d[j] = *(const uint4*)(Xe + (size_t)src * NHID + lr * 8);
            }
#pragma unroll
            for (int j = 0; j < 4; ++j)
                if (jb * 4 + j < m) ACC8(d[j]);
        }
    }
    const float inv = 1.f / (float)max(end - beg, 1);
    float mk[8], s = 0.f;
#pragma unroll
    for (int k = 0; k < 8; ++k) { mk[k] = a[k] * inv; s += mk[k] * mk[k]; }
    s += __shfl_xor(s, 1); s += __shfl_xor(s, 2);
    s += __shfl_xor(s, 4); s += __shfl_xor(s, 8);
    const float norm = sqrtf(s);
    const float scale = norm > 0.f ? 1.f / fmaxf(norm, 1e-30f) : 0.f;
    float xv[8];
    xv[0] = u2f(u0.x << 16); xv[1] = u2f(u0.x & 0xffff0000u);
    xv[2] = u2f(u0.y << 16); xv[3] = u2f(u0.y & 0xffff0000u);
    xv[4] = u2f(u0.z << 16); xv[5] = u2f(u0.z & 0xffff0000u);
    xv[6] = u2f(u0.w << 16); xv[7] = u2f(u0.w & 0xffff0000u);
    float o[8];
#pragma unroll
    for (int k = 0; k < 8; ++k) o[k] = 0.9f * mk[k] * scale + 0.1f * xv[k];
    uint4 ou;
    ou.x = pk2(o[0], o[1]); ou.y = pk2(o[2], o[3]);
    ou.z = pk2(o[4], o[5]); ou.w = pk2(o[6], o[7]);
    *(uint4*)(xl + row * XL_STRIDE + lr * 8) = ou;
}

// ---- K6: node gather+post fused with layer-1 GEMM ----
__global__ __launch_bounds__(256)
void node_l1_kernel(const ushort_t* __restrict__ Xe, const int* __restrict__ rp,
                    const ushort_t* __restrict__ ci, const ushort_t* __restrict__ x0,
                    const int* __restrict__ vperm,
                    const ushort_t* __restrict__ Wt, float beta,
                    ushort_t* __restrict__ xout) {
    __shared__ ushort_t xl[16 * XL_STRIDE];
    __shared__ int vmap[16];
    const int vbase = blockIdx.x * 16;
    node_phase1(Xe, rp, ci, x0, vperm, vbase, xl, vmap);
    __syncthreads();
    const int lane = threadIdx.x & 63, wave = threadIdx.x >> 6;
    const int r = lane & 15, kb = lane >> 4;
    bf16x8 a2[4];
#pragma unroll
    for (int k0 = 0; k0 < 4; ++k0)
        a2[k0] = *(const bf16x8*)(xl + r * XL_STRIDE + k0 * 32 + kb * 8);
    f32x4 acc[2] = {};
#pragma unroll
    for (int k0 = 0; k0 < 4; ++k0)
#pragma unroll
        for (int cc = 0; cc < 2; ++cc) {
            const int c0 = wave * 2 + cc;
            const bf16x8 b = *(const bf16x8*)(Wt + (size_t)(c0 * 16 + r) * NHID + k0 * 32 + kb * 8);
            acc[cc] = __builtin_amdgcn_mfma_f32_16x16x32_bf16(a2[k0], b, acc[cc], 0, 0, 0);
        }
    const float xim = 1.f - beta;
#pragma unroll
    for (int cc = 0; cc < 2; ++cc) {
        const int col = (wave * 2 + cc) * 16 + r;
#pragma unroll
        for (int v = 0; v < 4; ++v) {
            const int row = kb * 4 + v;
            const float xi = us2f(xl[row * XL_STRIDE + col]);
            float val = xim * xi + beta * acc[cc][v];
            val = val > 0.f ? val : 0.f;
            xout[(size_t)vmap[row] * NHID + col] = f2b(val);
        }
    }
}

// ---- K8: node gather+post fused with layer-2 GEMM AND output GEMM ----
__global__ __launch_bounds__(256)
void node_l2_out_kernel(const ushort_t* __restrict__ Xe, const int* __restrict__ rp,
                        const ushort_t* __restrict__ ci, const ushort_t* __restrict__ x0,
                        const int* __restrict__ vperm,
                        const ushort_t* __restrict__ Wt, const ushort_t* __restrict__ WoT,
                        const float* __restrict__ bias, float beta,
                        float* __restrict__ out) {
    __shared__ ushort_t xl[16 * XL_STRIDE];
    __shared__ ushort_t x2[16 * XL_STRIDE];
    __shared__ int vmap[16];
    const int vbase = blockIdx.x * 16;
    node_phase1(Xe, rp, ci, x0, vperm, vbase, xl, vmap);
    __syncthreads();
    const int lane = threadIdx.x & 63, wave = threadIdx.x >> 6;
    const int r = lane & 15, kb = lane >> 4;
    {
        bf16x8 a2[4];
#pragma unroll
        for (int k0 = 0; k0 < 4; ++k0)
            a2[k0] = *(const bf16x8*)(xl + r * XL_STRIDE + k0 * 32 + kb * 8);
        f32x4 acc[2] = {};
#pragma unroll
        for (int k0 = 0; k0 < 4; ++k0)
#pragma unroll
            for (int cc = 0; cc < 2; ++cc) {
                const int c0 = wave * 2 + cc;
                const bf16x8 b = *(const bf16x8*)(Wt + (size_t)(c0 * 16 + r) * NHID + k0 * 32 + kb * 8);
                acc[cc] = __builtin_amdgcn_mfma_f32_16x16x32_bf16(a2[k0], b, acc[cc], 0, 0, 0);
            }
        const float xim = 1.f - beta;
#pragma unroll
        for (int cc = 0; cc < 2; ++cc) {
            const int col = (wave * 2 + cc) * 16 + r;
#pragma unroll
            for (int v = 0; v < 4; ++v) {
                const int row = kb * 4 + v;
                const float xi = us2f(xl[row * XL_STRIDE + col]);
                float val = xim * xi + beta * acc[cc][v];
                val = val > 0.f ? val : 0.f;
                x2[row * XL_STRIDE + col] = f2b(val);
            }
        }
    }
    __syncthreads();
    bf16x8 a3[4];
#pragma unroll
    for (int k0 = 0; k0 < 4; ++k0)
        a3[k0] = *(const bf16x8*)(x2 + r * XL_STRIDE + k0 * 32 + kb * 8);
    const float bv = bias[wave * 16 + r];
    f32x4 facc = (f32x4){bv, bv, bv, bv};
#pragma unroll
    for (int k0 = 0; k0 < 4; ++k0) {
        const bf16x8 b = *(const bf16x8*)(WoT + (size_t)(wave * 16 + r) * NHID + k0 * 32 + kb * 8);
        facc = __builtin_amdgcn_mfma_f32_16x16x32_bf16(a3[k0], b, facc, 0, 0, 0);
    }
#pragma unroll
    for (int v = 0; v < 4; ++v) {
        const int row = kb * 4 + v;
        out[(size_t)vmap[row] * FOUT + wave * 16 + r] = facc[v];
    }
}

extern "C" void kernel_launch(void* const* d_in, const int* in_sizes, int n_in,
                              void* d_out, int out_size, void* d_ws, size_t ws_size,
                              hipStream_t stream) {
    const float* x_in  = (const float*)d_in[0];
    const float* W0    = (const float*)d_in[1];
    const float* b0    = (const float*)d_in[2];
    const float* Ws    = (const float*)d_in[3];
    const float* Wout  = (const float*)d_in[4];
    const float* bout  = (const float*)d_in[5];
    const int* vertex  = (const int*)d_in[6];
    const int* edges   = (const int*)d_in[7];

    ushort_t* Xe   = (ushort_t*)d_ws;                       // EDGES*NHID bf16
    ushort_t* x    = Xe + (size_t)EDGES * NHID;             // NODES*NHID bf16
    ushort_t* x0   = x  + (size_t)NODES * NHID;             // NODES*NHID bf16
    ushort_t* Wt0  = x0 + (size_t)NODES * NHID;             // 128*128
    ushort_t* WsT  = Wt0 + 128 * 128;                       // 2*128*128
    ushort_t* WoutT= WsT + 2 * 128 * 128;                   // 64*128
    int* cnt_e = (int*)(WoutT + 64 * 128);                  // EDGES
    int* cnt_v = cnt_e + EDGES;                             // NODES
    int* rp_e  = cnt_v + NODES;                             // EDGES+1 (pad to 10004)
    int* rp_v  = rp_e + EDGES + 4;                          // NODES+1 (pad to 50004)
    int* cnt_se = rp_v + NODES + 4;                         // NPART*NSLICE = 1024
    int* cnt_sv = cnt_se + NPART * NSLICE;                  // 1024
    int* dhist  = cnt_sv + NPART * NSLICE;                  // 256
    int* bcur   = dhist + 256;                              // 256
    int* vperm  = bcur + 256;                               // NODES
    uint_t* cbe = (uint_t*)(vperm + NODES);                 // NSLICE*EWORDS = 640K words
    uint_t* cbv = cbe + (size_t)NSLICE * EWORDS;            // NPART*VSUB*VPW = 400K words
    uint_t* stage_e = cbv + (size_t)NPART * VSUB * VPW;     // 4 MB
    uint_t* stage_v = stage_e + (size_t)NPART * NSLICE * CAP; // 4 MB
    ushort_t* col_e = (ushort_t*)(stage_v + (size_t)NPART * NSLICE * CAP);  // NNZ u16
    ushort_t* col_v = col_e + NNZ;                          // NNZ u16

    float* out    = (float*)d_out;                          // [NODES, FOUT]
    float* out_xe = out + (size_t)NODES * FOUT;             // [EDGES, NHID]

    hipMemsetAsync(dhist, 0, 256 * sizeof(int), stream);

    // K1: one pass over entries (edge hist + radix staging) + weight conversion
    hist_stage_wconv_kernel<<<NSLICE + WCONV_BLOCKS, 256, 0, stream>>>(
        vertex, edges, cbe, stage_e, stage_v, cnt_se, cnt_sv,
        W0, Ws, Wout, Wt0, WsT, WoutT);
    // K1.5: vertex hist (per partition, from staged) + edge colscan
    vhist_colscane_kernel<<<VFILL + (EWORDS + 255) / 256, 256, 0, stream>>>(
        stage_v, cnt_sv, cbv, cbe, cnt_e);
    // K2a: vertex colscan
    colscanv_kernel<<<(NPART * VPW + 255) / 256, 256, 0, stream>>>(cbv, cnt_v);
    // K2b: rp scans + degree histogram
    scan2_hist_kernel<<<2 + NHIST, 1024, 0, stream>>>(cnt_e, rp_e, cnt_v, rp_v, dhist);
    // K2c: bin scan -> bucket cursors
    binscan_kernel<<<1, 256, 0, stream>>>(dhist, bcur);
    // K3: fill both CSRs + input GEMM + vperm fill (hierarchical counting sort)
    fill_gemm_kernel<<<EFILL + VFILL + GEMM_BLOCKS + PERMF_BLOCKS, 256, 0, stream>>>(
        stage_e, stage_v, cnt_se, cnt_sv, cbe, cbv, rp_e, rp_v,
        col_e, col_v, x_in, Wt0, b0, x0, cnt_v, bcur, vperm);

    const float betas[2] = {logf(1.5f), logf(1.25f)};  // log(0.5/(i+1)+1)

    // layer 1
    edge_gather_kernel<<<EDGE_BLOCKS, 256, 0, stream>>>(x0, rp_e, col_e, Xe, (float*)nullptr);
    node_l1_kernel<<<NF_BLOCKS, 256, 0, stream>>>(Xe, rp_v, col_v, x0, vperm, WsT, betas[0], x);
    // layer 2
    edge_gather_kernel<<<EDGE_BLOCKS, 256, 0, stream>>>(x, rp_e, col_e, Xe, out_xe);
    node_l2_out_kernel<<<NF_BLOCKS, 256, 0, stream>>>(
        Xe, rp_v, col_v, x0, vperm, WsT + (size_t)NHID * NHID, WoutT, bout, betas[1], out);
}

// Round 21
// 200.518 us; speedup vs baseline: 1.7066x; 1.0279x over previous
//
#include <hip/hip_runtime.h>
#include <hip/hip_bf16.h>
#include <math.h>

#define NODES 50000
#define EDGES 10000
#define NNZ   800000
#define FIN   128
#define NHID  128
#define FOUT  64

#define NPART  8                   // key partitions == XCDs (blockIdx%8 binding in fill)
#define NSLICE 128                 // entry slices (read once each)
#define SLICE  (NNZ / NSLICE)      // 6250
#define CAP    1024                // staging bucket capacity (mean 781, +9 sigma)
#define EP     (EDGES / NPART)     // 1250 edge keys / partition
#define EWORDS (EDGES / 2)         // 5000 packed hist words (full edge range)
#define VP     (NODES / NPART)     // 6250 vertex keys / partition
#define VPW    (VP / 2)            // 3125 packed words
#define VSUB   16                  // vertex sub-blocks per partition
#define SLPER  (NSLICE / VSUB)     // 8 slices per sub-block

#define EFILL  (NPART * NSLICE)    // 1024 edge-fill blocks
#define VFILL  (NPART * VSUB)      // 128 vertex-fill blocks
#define WCONV_BLOCKS 128
#define GEMM_BLOCKS  ((NODES + 63) / 64)  // 782
#define EDGE_BLOCKS  (EDGES * 64 / 256)   // 2500
#define NF_BLOCKS    (NODES / 16)         // 3125

#define XL_STRIDE 144              // LDS row stride in ushorts

typedef __attribute__((ext_vector_type(8))) short bf16x8;
typedef __attribute__((ext_vector_type(4))) float f32x4;
typedef unsigned short ushort_t;
typedef unsigned int uint_t;

__device__ __forceinline__ ushort_t f2b(float f) {
    __hip_bfloat16 h = __float2bfloat16(f);
    return *reinterpret_cast<ushort_t*>(&h);
}
__device__ __forceinline__ float u2f(unsigned u) {
    union { unsigned u; float f; } c; c.u = u; return c.f;
}
__device__ __forceinline__ float us2f(ushort_t u) { return u2f((unsigned)u << 16); }
__device__ __forceinline__ unsigned pk2(float lo, float hi) {
    return (unsigned)f2b(lo) | ((unsigned)f2b(hi) << 16);
}
#define ACC8(d)                                             \
    do {                                                    \
        a[0] += u2f((d).x << 16); a[1] += u2f((d).x & 0xffff0000u); \
        a[2] += u2f((d).y << 16); a[3] += u2f((d).y & 0xffff0000u); \
        a[4] += u2f((d).z << 16); a[5] += u2f((d).z & 0xffff0000u); \
        a[6] += u2f((d).w << 16); a[7] += u2f((d).w & 0xffff0000u); \
    } while (0)

// ---- K1: one pass over entries: edge hist (LDS) + radix-stage both sides | wconv ----
__global__ __launch_bounds__(256)
void hist_stage_wconv_kernel(const int* __restrict__ vertex, const int* __restrict__ edges,
                             uint_t* __restrict__ cbe,
                             uint_t* __restrict__ stage_e, uint_t* __restrict__ stage_v,
                             int* __restrict__ cnt_se, int* __restrict__ cnt_sv,
                             const float* __restrict__ W0, const float* __restrict__ Ws,
                             const float* __restrict__ Wout,
                             ushort_t* __restrict__ Wt0, ushort_t* __restrict__ WsT,
                             ushort_t* __restrict__ WoutT) {
    __shared__ uint_t eh[EWORDS];       // 20 KB packed edge hist
    __shared__ uint_t cse[NPART], csv[NPART];
    const int t = threadIdx.x;
    if (blockIdx.x < NSLICE) {
        const int b = blockIdx.x;
        for (int w = t; w < EWORDS; w += 256) eh[w] = 0;
        if (t < NPART) { cse[t] = 0; csv[t] = 0; }
        __syncthreads();
        const int base = b * SLICE;
        for (int i = base + t; i < base + SLICE; i += 256) {
            const int e = edges[i], v = vertex[i];
            atomicAdd(&eh[e >> 1], 1u << ((e & 1) * 16));
            const int pe = e / EP;
            const uint_t pose = atomicAdd(&cse[pe], 1u);
            stage_e[(size_t)(pe * NSLICE + b) * CAP + pose] = ((uint_t)e << 16) | (uint_t)v;
            const int pv = v / VP;
            const uint_t posv = atomicAdd(&csv[pv], 1u);
            stage_v[(size_t)(pv * NSLICE + b) * CAP + posv] = ((uint_t)v << 16) | (uint_t)e;
        }
        __syncthreads();
        for (int w = t; w < EWORDS; w += 256) cbe[b * EWORDS + w] = eh[w];
        if (t < NPART) {
            cnt_se[t * NSLICE + b] = (int)cse[t];
            cnt_sv[t * NSLICE + b] = (int)csv[t];
        }
    } else {                                     // ---- weight transpose/convert ----
        const int i = (blockIdx.x - NSLICE) * 256 + t;
        if (i < 128 * 128) { int c = i >> 7, k = i & 127; Wt0[c * 128 + k] = f2b(W0[k * 128 + c]); }
        if (i < 2 * 128 * 128) {
            int l = i >> 14, r = i & 16383, c = r >> 7, k = r & 127;
            WsT[l * 16384 + c * 128 + k] = f2b(Ws[l * 16384 + k * 128 + c]);
        }
        if (i < 64 * 128) { int c = i >> 7, k = i & 127; WoutT[c * 128 + k] = f2b(Wout[k * 64 + c]); }
    }
}

// ---- K1.5: per-partition vertex hist from staged data | colscan of edge counts ----
__global__ __launch_bounds__(256)
void vhist_colscane_kernel(const uint_t* __restrict__ stage_v, const int* __restrict__ cnt_sv,
                           uint_t* __restrict__ cbv,
                           uint_t* __restrict__ cbe, int* __restrict__ cnt_e) {
    const int t = threadIdx.x;
    if (blockIdx.x < VFILL) {                    // 128 vertex-hist blocks
        __shared__ uint_t vh[VPW];               // 12.5 KB
        const int p = blockIdx.x & 7, s = blockIdx.x >> 3;
        for (int w = t; w < VPW; w += 256) vh[w] = 0;
        __syncthreads();
        for (int sl = s * SLPER; sl < (s + 1) * SLPER; ++sl) {
            const int n = cnt_sv[p * NSLICE + sl];
            const uint_t* sv = stage_v + (size_t)(p * NSLICE + sl) * CAP;
            for (int j = t; j < n; j += 256) {
                const int vk = (int)(sv[j] >> 16) - p * VP;
                atomicAdd(&vh[vk >> 1], 1u << ((vk & 1) * 16));
            }
        }
        __syncthreads();
        for (int w = t; w < VPW; w += 256)
            cbv[(size_t)(p * VSUB + s) * VPW + w] = vh[w];
    } else {                                     // colscan over edge slice-counts
        const int flat = (blockIdx.x - VFILL) * 256 + t;
        if (flat < EWORDS) {
            uint_t s0 = 0, s1 = 0;
            for (int b = 0; b < NSLICE; ++b) {
                uint_t* q = &cbe[b * EWORDS + flat];
                const uint_t u = *q; *q = s0 | (s1 << 16);
                s0 += u & 0xffffu; s1 += u >> 16;
            }
            cnt_e[2 * flat]     = (int)s0;
            cnt_e[2 * flat + 1] = (int)s1;
        }
    }
}

// ---- K2a: colscan of vertex sub-block counts ----
__global__ __launch_bounds__(256)
void colscanv_kernel(uint_t* __restrict__ cbv, int* __restrict__ cnt_v) {
    const int flat = blockIdx.x * 256 + (int)threadIdx.x;
    if (flat < NPART * VPW) {
        const int p = flat / VPW, w = flat % VPW;
        uint_t s0 = 0, s1 = 0;
        for (int s = 0; s < VSUB; ++s) {
            uint_t* q = &cbv[(size_t)(p * VSUB + s) * VPW + w];
            const uint_t u = *q; *q = s0 | (s1 << 16);
            s0 += u & 0xffffu; s1 += u >> 16;
        }
        cnt_v[p * VP + 2 * w]     = (int)s0;
        cnt_v[p * VP + 2 * w + 1] = (int)s1;
    }
}

// ---- exclusive scan, 8 items/thread, single 1024-thread block ----
__device__ __forceinline__ void scan_impl(const int* __restrict__ cnt, int* __restrict__ rp,
                                          const int n) {
    __shared__ int wsum[16];
    __shared__ int carry_sh;
    const int t = threadIdx.x, lane = t & 63, w = t >> 6;
    if (t == 0) carry_sh = 0;
    __syncthreads();
    for (int base = 0; base < n; base += 8192) {
        const int idx = base + t * 8;
        int v[8];
        if (idx + 8 <= n) {
            const int4 a = *(const int4*)(cnt + idx);
            const int4 b = *(const int4*)(cnt + idx + 4);
            v[0] = a.x; v[1] = a.y; v[2] = a.z; v[3] = a.w;
            v[4] = b.x; v[5] = b.y; v[6] = b.z; v[7] = b.w;
        } else {
#pragma unroll
            for (int j = 0; j < 8; ++j) v[j] = (idx + j < n) ? cnt[idx + j] : 0;
        }
        int sum8 = 0;
#pragma unroll
        for (int j = 0; j < 8; ++j) sum8 += v[j];
        int x = sum8;
#pragma unroll
        for (int o = 1; o < 64; o <<= 1) {
            int y = __shfl_up(x, o);
            if (lane >= o) x += y;
        }
        if (lane == 63) wsum[w] = x;
        __syncthreads();
        if (t < 16) {
            int s = wsum[t];
#pragma unroll
            for (int o = 1; o < 16; o <<= 1) {
                int y = __shfl_up(s, o);
                if (t >= o) s += y;
            }
            wsum[t] = s;
        }
        __syncthreads();
        const int carry = carry_sh;
        int pre = carry + (x - sum8) + (w ? wsum[w - 1] : 0);
        if (idx < n) {
#pragma unroll
            for (int j = 0; j < 8; ++j)
                if (idx + j < n) { rp[idx + j] = pre; pre += v[j]; }
        }
        __syncthreads();
        if (t == 1023) carry_sh = carry + wsum[15];
        __syncthreads();
    }
    if (t == 0) rp[n] = carry_sh;
}

// ---- K2b: both rp scans ----
__global__ __launch_bounds__(1024)
void scan2_kernel(const int* __restrict__ cnt_e, int* __restrict__ rp_e,
                  const int* __restrict__ cnt_v, int* __restrict__ rp_v) {
    if (blockIdx.x == 0) scan_impl(cnt_e, rp_e, EDGES);
    else                 scan_impl(cnt_v, rp_v, NODES);
}

// ---- K3: fill both CSRs from staged data (XCD-local scatter) | input GEMM ----
__global__ __launch_bounds__(256)
void fill_gemm_kernel(const uint_t* __restrict__ stage_e, const uint_t* __restrict__ stage_v,
                      const int* __restrict__ cnt_se, const int* __restrict__ cnt_sv,
                      const uint_t* __restrict__ cbe, const uint_t* __restrict__ cbv,
                      const int* __restrict__ rp_e, const int* __restrict__ rp_v,
                      ushort_t* __restrict__ col_e, ushort_t* __restrict__ col_v,
                      const float* __restrict__ X, const ushort_t* __restrict__ Wt,
                      const float* __restrict__ bias, ushort_t* __restrict__ x0) {
    __shared__ uint_t cur[VP];   // 25 KB (e-fill uses first EP)
    const int t = threadIdx.x;
    if (blockIdx.x < EFILL) {                    // ---- edge fill (p = blockIdx%8 -> XCD) ----
        const int p = blockIdx.x & 7, sl = blockIdx.x >> 3;
        for (int k = t; k < EP; k += 256) {
            const int key = p * EP + k;
            const uint_t word = cbe[sl * EWORDS + (key >> 1)];
            const uint_t b16 = (k & 1) ? (word >> 16) : (word & 0xffffu);
            cur[k] = (uint_t)rp_e[key] + b16;
        }
        __syncthreads();
        const int n = cnt_se[p * NSLICE + sl];
        const uint_t* se = stage_e + (size_t)(p * NSLICE + sl) * CAP;
        for (int j = t; j < n; j += 256) {
            const uint_t u = se[j];
            const uint_t pos = atomicAdd(&cur[(int)(u >> 16) - p * EP], 1u);
            col_e[pos] = (ushort_t)(u & 0xffffu);
        }
        return;
    }
    if (blockIdx.x < EFILL + VFILL) {            // ---- vertex fill ----
        const int vb = blockIdx.x - EFILL;       // EFILL%8==0 keeps %8 binding
        const int p = vb & 7, s = vb >> 3;
        for (int k = t; k < VP; k += 256) {
            const int key = p * VP + k;
            const uint_t word = cbv[(size_t)(p * VSUB + s) * VPW + (k >> 1)];
            const uint_t b16 = (k & 1) ? (word >> 16) : (word & 0xffffu);
            cur[k] = (uint_t)rp_v[key] + b16;
        }
        __syncthreads();
        for (int sl = s * SLPER; sl < (s + 1) * SLPER; ++sl) {
            const int n = cnt_sv[p * NSLICE + sl];
            const uint_t* sv = stage_v + (size_t)(p * NSLICE + sl) * CAP;
            for (int j = t; j < n; j += 256) {
                const uint_t u = sv[j];
                const uint_t pos = atomicAdd(&cur[(int)(u >> 16) - p * VP], 1u);
                col_v[pos] = (ushort_t)(u & 0xffffu);
            }
        }
        return;
    }
    // ---- input GEMM: x0 = relu(Xin @ W0 + b0) ----
    const int lane = threadIdx.x & 63, wave = threadIdx.x >> 6;
    const int row0 = (blockIdx.x - (EFILL + VFILL)) * 64 + wave * 16;
    if (row0 >= NODES) return;
    const int r = lane & 15, kb = lane >> 4;
    const int row = row0 + r;
    bf16x8 a[4];
#pragma unroll
    for (int k0 = 0; k0 < 4; ++k0) {
        const float* p = X + (size_t)row * FIN + k0 * 32 + kb * 8;
        const float4 lo = *(const float4*)p;
        const float4 hi = *(const float4*)(p + 4);
        bf16x8 tt;
        tt[0] = f2b(lo.x); tt[1] = f2b(lo.y); tt[2] = f2b(lo.z); tt[3] = f2b(lo.w);
        tt[4] = f2b(hi.x); tt[5] = f2b(hi.y); tt[6] = f2b(hi.z); tt[7] = f2b(hi.w);
        a[k0] = tt;
    }
    f32x4 acc[8];
#pragma unroll
    for (int c0 = 0; c0 < 8; ++c0) {
        const float bv = bias[c0 * 16 + r];
        acc[c0] = (f32x4){bv, bv, bv, bv};
    }
#pragma unroll
    for (int k0 = 0; k0 < 4; ++k0)
#pragma unroll
        for (int c0 = 0; c0 < 8; ++c0) {
            const bf16x8 b = *(const bf16x8*)(Wt + (size_t)(c0 * 16 + r) * FIN + k0 * 32 + kb * 8);
            acc[c0] = __builtin_amdgcn_mfma_f32_16x16x32_bf16(a[k0], b, acc[c0], 0, 0, 0);
        }
#pragma unroll
    for (int c0 = 0; c0 < 8; ++c0) {
        const int col = c0 * 16 + r;
#pragma unroll
        for (int v = 0; v < 4; ++v) {
            const int orow = row0 + kb * 4 + v;
            float val = acc[c0][v];
            val = val > 0.f ? val : 0.f;
            x0[(size_t)orow * NHID + col] = f2b(val);
        }
    }
}

// ---- edge gather: 16 lanes/row, 4-deep load batches, 4 rows in flight per wave ----
__global__ __launch_bounds__(256)
void edge_gather_kernel(const ushort_t* __restrict__ x, const int* __restrict__ rp,
                        const ushort_t* __restrict__ ci, ushort_t* __restrict__ Xe,
                        float* __restrict__ out_xe) {
    const int e = (blockIdx.x * 256 + (int)threadIdx.x) >> 6;
    if (e >= EDGES) return;
    const int lane = threadIdx.x & 63;
    const int sub = lane >> 4, lr = lane & 15;
    const int beg = rp[e], end = rp[e + 1];
    float a[8] = {};
    for (int base = beg; base < end; base += 64) {
        const int m = min(64, end - base);
        const int idx_l = (lane < m) ? (int)ci[base + lane] : 0;
#pragma unroll
        for (int jb = 0; jb < 4; ++jb) {         // 4 batches of 4 in-flight loads
            uint4 d[4];
#pragma unroll
            for (int j = 0; j < 4; ++j) {
                const int slot = (jb * 4 + j) * 4 + sub;
                const int src = __shfl(idx_l, slot & 63);
                if (slot < m) d[j] = *(const uint4*)(x + (size_t)src * NHID + lr * 8);
            }
#pragma unroll
            for (int j = 0; j < 4; ++j)
                if ((jb * 4 + j) * 4 + sub < m) ACC8(d[j]);
        }
    }
#pragma unroll
    for (int k = 0; k < 8; ++k) {
        a[k] += __shfl_xor(a[k], 16);
        a[k] += __shfl_xor(a[k], 32);
    }
    const float inv = 1.f / (float)max(end - beg, 1);
    if (sub == 0) {
        float vv[8];
#pragma unroll
        for (int k = 0; k < 8; ++k) vv[k] = a[k] * inv;
        uint4 o;
        o.x = pk2(vv[0], vv[1]); o.y = pk2(vv[2], vv[3]);
        o.z = pk2(vv[4], vv[5]); o.w = pk2(vv[6], vv[7]);
        *(uint4*)(Xe + (size_t)e * NHID + lr * 8) = o;
        if (out_xe) {
            const float4 f0 = {vv[0], vv[1], vv[2], vv[3]};
            const float4 f1 = {vv[4], vv[5], vv[6], vv[7]};
            *(float4*)(out_xe + (size_t)e * NHID + lr * 8) = f0;
            *(float4*)(out_xe + (size_t)e * NHID + lr * 8 + 4) = f1;
        }
    }
}

// ---- node phase 1: gather (4-deep batches) + mean + L2-norm + residual -> LDS ----
__device__ __forceinline__ void node_phase1(const ushort_t* __restrict__ Xe,
                                            const int* __restrict__ rp,
                                            const ushort_t* __restrict__ ci,
                                            const ushort_t* __restrict__ x0,
                                            const int vbase,
                                            ushort_t* __restrict__ xl) {
    const int lane = threadIdx.x & 63, wave = threadIdx.x >> 6;
    const int sub = lane >> 4, lr = lane & 15;
    const int row = wave * 4 + sub;
    const int v = vbase + row;
    const int beg = rp[v], end = rp[v + 1];
    const int sbase = lane & 48;
    // prefetch x0 row (independent of gather)
    const uint4 u0 = *(const uint4*)(x0 + (size_t)v * NHID + lr * 8);
    float a[8] = {};
    for (int base = beg; base < end; base += 16) {
        const int m = min(16, end - base);
        const int idx_l = (lr < m) ? (int)ci[base + lr] : 0;
#pragma unroll
        for (int jb = 0; jb < 4; ++jb) {         // 4 batches of 4 in-flight loads
            uint4 d[4];
#pragma unroll
            for (int j = 0; j < 4; ++j) {
                const int slot = jb * 4 + j;
                const int src = __shfl(idx_l, sbase + slot);
                if (slot < m) d[j] = *(const uint4*)(Xe + (size_t)src * NHID + lr * 8);
            }
#pragma unroll
            for (int j = 0; j < 4; ++j)
                if (jb * 4 + j < m) ACC8(d[j]);
        }
    }
    const float inv = 1.f / (float)max(end - beg, 1);
    float mk[8], s = 0.f;
#pragma unroll
    for (int k = 0; k < 8; ++k) { mk[k] = a[k] * inv; s += mk[k] * mk[k]; }
    s += __shfl_xor(s, 1); s += __shfl_xor(s, 2);
    s += __shfl_xor(s, 4); s += __shfl_xor(s, 8);
    const float norm = sqrtf(s);
    const float scale = norm > 0.f ? 1.f / fmaxf(norm, 1e-30f) : 0.f;
    float xv[8];
    xv[0] = u2f(u0.x << 16); xv[1] = u2f(u0.x & 0xffff0000u);
    xv[2] = u2f(u0.y << 16); xv[3] = u2f(u0.y & 0xffff0000u);
    xv[4] = u2f(u0.z << 16); xv[5] = u2f(u0.z & 0xffff0000u);
    xv[6] = u2f(u0.w << 16); xv[7] = u2f(u0.w & 0xffff0000u);
    float o[8];
#pragma unroll
    for (int k = 0; k < 8; ++k) o[k] = 0.9f * mk[k] * scale + 0.1f * xv[k];
    uint4 ou;
    ou.x = pk2(o[0], o[1]); ou.y = pk2(o[2], o[3]);
    ou.z = pk2(o[4], o[5]); ou.w = pk2(o[6], o[7]);
    *(uint4*)(xl + row * XL_STRIDE + lr * 8) = ou;
}

// ---- K6: node gather+post fused with layer-1 GEMM ----
__global__ __launch_bounds__(256)
void node_l1_kernel(const ushort_t* __restrict__ Xe, const int* __restrict__ rp,
                    const ushort_t* __restrict__ ci, const ushort_t* __restrict__ x0,
                    const ushort_t* __restrict__ Wt, float beta,
                    ushort_t* __restrict__ xout) {
    __shared__ ushort_t xl[16 * XL_STRIDE];
    const int vbase = blockIdx.x * 16;
    node_phase1(Xe, rp, ci, x0, vbase, xl);
    __syncthreads();
    const int lane = threadIdx.x & 63, wave = threadIdx.x >> 6;
    const int r = lane & 15, kb = lane >> 4;
    bf16x8 a2[4];
#pragma unroll
    for (int k0 = 0; k0 < 4; ++k0)
        a2[k0] = *(const bf16x8*)(xl + r * XL_STRIDE + k0 * 32 + kb * 8);
    f32x4 acc[2] = {};
#pragma unroll
    for (int k0 = 0; k0 < 4; ++k0)
#pragma unroll
        for (int cc = 0; cc < 2; ++cc) {
            const int c0 = wave * 2 + cc;
            const bf16x8 b = *(const bf16x8*)(Wt + (size_t)(c0 * 16 + r) * NHID + k0 * 32 + kb * 8);
            acc[cc] = __builtin_amdgcn_mfma_f32_16x16x32_bf16(a2[k0], b, acc[cc], 0, 0, 0);
        }
    const float xim = 1.f - beta;
#pragma unroll
    for (int cc = 0; cc < 2; ++cc) {
        const int col = (wave * 2 + cc) * 16 + r;
#pragma unroll
        for (int v = 0; v < 4; ++v) {
            const int row = kb * 4 + v;
            const float xi = us2f(xl[row * XL_STRIDE + col]);
            float val = xim * xi + beta * acc[cc][v];
            val = val > 0.f ? val : 0.f;
            xout[(size_t)(vbase + row) * NHID + col] = f2b(val);
        }
    }
}

// ---- K8: node gather+post fused with layer-2 GEMM AND output GEMM ----
__global__ __launch_bounds__(256)
void node_l2_out_kernel(const ushort_t* __restrict__ Xe, const int* __restrict__ rp,
                        const ushort_t* __restrict__ ci, const ushort_t* __restrict__ x0,
                        const ushort_t* __restrict__ Wt, const ushort_t* __restrict__ WoT,
                        const float* __restrict__ bias, float beta,
                        float* __restrict__ out) {
    __shared__ ushort_t xl[16 * XL_STRIDE];
    __shared__ ushort_t x2[16 * XL_STRIDE];
    const int vbase = blockIdx.x * 16;
    node_phase1(Xe, rp, ci, x0, vbase, xl);
    __syncthreads();
    const int lane = threadIdx.x & 63, wave = threadIdx.x >> 6;
    const int r = lane & 15, kb = lane >> 4;
    {
        bf16x8 a2[4];
#pragma unroll
        for (int k0 = 0; k0 < 4; ++k0)
            a2[k0] = *(const bf16x8*)(xl + r * XL_STRIDE + k0 * 32 + kb * 8);
        f32x4 acc[2] = {};
#pragma unroll
        for (int k0 = 0; k0 < 4; ++k0)
#pragma unroll
            for (int cc = 0; cc < 2; ++cc) {
                const int c0 = wave * 2 + cc;
                const bf16x8 b = *(const bf16x8*)(Wt + (size_t)(c0 * 16 + r) * NHID + k0 * 32 + kb * 8);
                acc[cc] = __builtin_amdgcn_mfma_f32_16x16x32_bf16(a2[k0], b, acc[cc], 0, 0, 0);
            }
        const float xim = 1.f - beta;
#pragma unroll
        for (int cc = 0; cc < 2; ++cc) {
            const int col = (wave * 2 + cc) * 16 + r;
#pragma unroll
            for (int v = 0; v < 4; ++v) {
                const int row = kb * 4 + v;
                const float xi = us2f(xl[row * XL_STRIDE + col]);
                float val = xim * xi + beta * acc[cc][v];
                val = val > 0.f ? val : 0.f;
                x2[row * XL_STRIDE + col] = f2b(val);
            }
        }
    }
    __syncthreads();
    bf16x8 a3[4];
#pragma unroll
    for (int k0 = 0; k0 < 4; ++k0)
        a3[k0] = *(const bf16x8*)(x2 + r * XL_STRIDE + k0 * 32 + kb * 8);
    const float bv = bias[wave * 16 + r];
    f32x4 facc = (f32x4){bv, bv, bv, bv};
#pragma unroll
    for (int k0 = 0; k0 < 4; ++k0) {
        const bf16x8 b = *(const bf16x8*)(WoT + (size_t)(wave * 16 + r) * NHID + k0 * 32 + kb * 8);
        facc = __builtin_amdgcn_mfma_f32_16x16x32_bf16(a3[k0], b, facc, 0, 0, 0);
    }
#pragma unroll
    for (int v = 0; v < 4; ++v) {
        const int row = kb * 4 + v;
        out[(size_t)(vbase + row) * FOUT + wave * 16 + r] = facc[v];
    }
}

extern "C" void kernel_launch(void* const* d_in, const int* in_sizes, int n_in,
                              void* d_out, int out_size, void* d_ws, size_t ws_size,
                              hipStream_t stream) {
    const float* x_in  = (const float*)d_in[0];
    const float* W0    = (const float*)d_in[1];
    const float* b0    = (const float*)d_in[2];
    const float* Ws    = (const float*)d_in[3];
    const float* Wout  = (const float*)d_in[4];
    const float* bout  = (const float*)d_in[5];
    const int* vertex  = (const int*)d_in[6];
    const int* edges   = (const int*)d_in[7];

    ushort_t* Xe   = (ushort_t*)d_ws;                       // EDGES*NHID bf16
    ushort_t* x    = Xe + (size_t)EDGES * NHID;             // NODES*NHID bf16
    ushort_t* x0   = x  + (size_t)NODES * NHID;             // NODES*NHID bf16
    ushort_t* Wt0  = x0 + (size_t)NODES * NHID;             // 128*128
    ushort_t* WsT  = Wt0 + 128 * 128;                       // 2*128*128
    ushort_t* WoutT= WsT + 2 * 128 * 128;                   // 64*128
    int* cnt_e = (int*)(WoutT + 64 * 128);                  // EDGES
    int* cnt_v = cnt_e + EDGES;                             // NODES
    int* rp_e  = cnt_v + NODES;                             // EDGES+1 (pad to 10004)
    int* rp_v  = rp_e + EDGES + 4;                          // NODES+1 (pad to 50004)
    int* cnt_se = rp_v + NODES + 4;                         // NPART*NSLICE = 1024
    int* cnt_sv = cnt_se + NPART * NSLICE;                  // 1024
    uint_t* cbe = (uint_t*)(cnt_sv + NPART * NSLICE);       // NSLICE*EWORDS = 640K words
    uint_t* cbv = cbe + (size_t)NSLICE * EWORDS;            // NPART*VSUB*VPW = 400K words
    uint_t* stage_e = cbv + (size_t)NPART * VSUB * VPW;     // 4 MB
    uint_t* stage_v = stage_e + (size_t)NPART * NSLICE * CAP; // 4 MB
    ushort_t* col_e = (ushort_t*)(stage_v + (size_t)NPART * NSLICE * CAP);  // NNZ u16
    ushort_t* col_v = col_e + NNZ;                          // NNZ u16

    float* out    = (float*)d_out;                          // [NODES, FOUT]
    float* out_xe = out + (size_t)NODES * FOUT;             // [EDGES, NHID]

    // K1: one pass over entries (edge hist + radix staging) + weight conversion
    hist_stage_wconv_kernel<<<NSLICE + WCONV_BLOCKS, 256, 0, stream>>>(
        vertex, edges, cbe, stage_e, stage_v, cnt_se, cnt_sv,
        W0, Ws, Wout, Wt0, WsT, WoutT);
    // K1.5: vertex hist (per partition, from staged) + edge colscan
    vhist_colscane_kernel<<<VFILL + (EWORDS + 255) / 256, 256, 0, stream>>>(
        stage_v, cnt_sv, cbv, cbe, cnt_e);
    // K2a: vertex colscan
    colscanv_kernel<<<(NPART * VPW + 255) / 256, 256, 0, stream>>>(cbv, cnt_v);
    // K2b: rp scans
    scan2_kernel<<<2, 1024, 0, stream>>>(cnt_e, rp_e, cnt_v, rp_v);
    // K3: fill both CSRs from staged data (XCD-local scatter) + input GEMM
    fill_gemm_kernel<<<EFILL + VFILL + GEMM_BLOCKS, 256, 0, stream>>>(
        stage_e, stage_v, cnt_se, cnt_sv, cbe, cbv, rp_e, rp_v,
        col_e, col_v, x_in, Wt0, b0, x0);

    const float betas[2] = {logf(1.5f), logf(1.25f)};  // log(0.5/(i+1)+1)

    // layer 1
    edge_gather_kernel<<<EDGE_BLOCKS, 256, 0, stream>>>(x0, rp_e, col_e, Xe, (float*)nullptr);
    node_l1_kernel<<<NF_BLOCKS, 256, 0, stream>>>(Xe, rp_v, col_v, x0, WsT, betas[0], x);
    // layer 2
    edge_gather_kernel<<<EDGE_BLOCKS, 256, 0, stream>>>(x, rp_e, col_e, Xe, out_xe);
    node_l2_out_kernel<<<NF_BLOCKS, 256, 0, stream>>>(
        Xe, rp_v, col_v, x0, WsT + (size_t)NHID * NHID, WoutT, bout, betas[1], out);
}